// Round 12
// baseline (29.354 us; speedup 1.0000x reference)
//
#include <hip/hip_runtime.h>
#include <hip/hip_bf16.h>

#define NN 262144
#define DD 32
#define HH 31
#define KK 21
#define ROWS 256                 // rows per block (2 chunks/thread in phase 1)
#define FSTRIDE 18               // u32 words per feats row (72 B)
#define WROW 36                  // shorts per W1T row (72 B, banks spread)
#define WK (32 * WROW)           // shorts per k = 1152
#define W1BF_B (KK * WK * 2)     // 48384 bytes
#define BW2_F (KK * 64)          // 1344 floats

typedef __attribute__((ext_vector_type(8))) short bf16x8;
typedef __attribute__((ext_vector_type(4))) float f32x4;
typedef __attribute__((ext_vector_type(2))) unsigned int u32x2;
typedef __attribute__((ext_vector_type(4))) unsigned int u32x4;

static __device__ __forceinline__ unsigned short f2bf(float f) {
    __hip_bfloat16 h = __float2bfloat16(f);      // round-to-nearest-even
    return __builtin_bit_cast(unsigned short, h);
}
static __device__ __forceinline__ unsigned pack2(float lo, float hi) {
    return (unsigned)f2bf(lo) | ((unsigned)f2bf(hi) << 16);
}

// ---------------- Prep: compact bf16 W1^T + {b1,w2} table ----------------
// gW1bf[k][e:32][d:36] = bf16(W1[k][d][e]), zero-padded. gbw2[k][0..31]=b1,
// [32..63]=w2 (padded).
__global__ __launch_bounds__(256) void prep_kernel(
    const float* __restrict__ W1, const float* __restrict__ b1,
    const float* __restrict__ W2,
    unsigned short* __restrict__ gW1bf, float* __restrict__ gbw2)
{
    const int k = (int)blockIdx.x;
    const int tid = (int)threadIdx.x;
    for (int idx = tid; idx < WK; idx += 256) {
        const int e = idx / WROW, d = idx % WROW;
        unsigned short v = 0;
        if (e < HH && d < HH) v = f2bf(W1[k * HH * HH + d * HH + e]);
        gW1bf[k * WK + idx] = v;
    }
    if (tid < 64) {
        const int e = tid & 31;
        float v = 0.0f;
        if (e < HH) v = (tid < 32) ? b1[k * HH + e] : W2[k * HH + e];
        gbw2[k * 64 + tid] = v;
    }
}

// ---------------- Fused: stage weights to LDS + sort + MFMA ----------------
__global__ __launch_bounds__(256, 2) void fused_kernel(
    const float* __restrict__ x,
    const float* __restrict__ a,
    const float* __restrict__ b,
    const float* __restrict__ b2,
    const unsigned short* __restrict__ gW1bf,
    const float* __restrict__ gbw2,
    float* __restrict__ out)
{
    __shared__ unsigned fbf[ROWS * FSTRIDE];                  // 18432 B
    __shared__ __align__(16) unsigned short sW1[KK * WK];     // 48384 B
    __shared__ __align__(16) float sbw2[BW2_F];               // 5376 B
    __shared__ int cnt[KK];
    __shared__ int rnk[KK];
    __shared__ int sbase[KK];
    __shared__ int tstart[KK + 1];
    __shared__ unsigned short sorted[ROWS];

    const int tid = (int)threadIdx.x;
    const int lane = tid & 63;
    const int rowbase = (int)blockIdx.x * ROWS;

    if (tid < KK) { cnt[tid] = 0; rnk[tid] = 0; }

    // ---- Stage weights (bulk coalesced, overlaps the x loads below) ----
    for (int i = tid; i < W1BF_B / 16; i += 256)
        ((u32x4*)sW1)[i] = ((const u32x4*)gW1bf)[i];
    for (int i = tid; i < BW2_F / 4; i += 256)
        ((f32x4*)sbw2)[i] = ((const f32x4*)gbw2)[i];

    // ---- Phase 1: 2 half-row chunks per thread, 64 B/lane coalesced ----
    const float edges[KK + 1] = {
        0.0f, 0.1f, 0.2f, 0.3f, 0.4f, 0.5f, 0.6f, 0.7f, 0.8f, 0.9f, 1.0f,
        1.1f, 1.2f, 1.3f, 1.4f, 1.5f, 1.6f, 1.7f, 1.8f, 1.9f, 2.0f, 1000.0f
    };
    int kq[2] = {-1, -1};
    #pragma unroll
    for (int i = 0; i < 2; ++i) {
        const int c    = tid + 256 * i;
        const int row  = c >> 1;
        const int half = c & 1;
        const float4* __restrict__ p =
            reinterpret_cast<const float4*>(x) + (size_t)blockIdx.x * (ROWS * DD / 4) + c * 4;
        float4 cc[4];
        #pragma unroll
        for (int j = 0; j < 4; ++j) cc[j] = p[j];

        // even lane receives odd lane's first element (x-elem 16 of the row)
        const float e16 = __shfl(cc[0].x, lane + 1);
        const float t = cc[0].x;

        if (half == 0) {
            int kk = -1;
            #pragma unroll
            for (int j = 0; j < KK; ++j)
                if (t > edges[j] && t <= edges[j + 1]) kk = j;
            kq[i] = kk;
            if (kk >= 0) atomicAdd(&cnt[kk], 1);
            else out[rowbase + row] = 0.0f;
        }

        unsigned* __restrict__ frow = fbf + row * FSTRIDE + half * 8;
        if (half == 0) {
            float f[16];
            #pragma unroll
            for (int j = 0; j < 15; ++j) {
                const float xe = ((const float*)cc)[j + 1];   // x-elems 1..15
                f[j] = fmaf(xe, a[j], b[j]);
            }
            f[15] = fmaf(e16, a[15], b[15]);
            #pragma unroll
            for (int s = 0; s < 8; ++s) frow[s] = pack2(f[2 * s], f[2 * s + 1]);
        } else {
            float f[16];
            #pragma unroll
            for (int j = 0; j < 15; ++j) {
                const float xe = ((const float*)cc)[j + 1];   // x-elems 17..31
                f[j] = fmaf(xe, a[16 + j], b[16 + j]);
            }
            f[15] = 0.0f;
            #pragma unroll
            for (int s = 0; s < 8; ++s) frow[s] = pack2(f[2 * s], f[2 * s + 1]);
        }
    }
    __syncthreads();

    // ---- Phase 2: wave-parallel scan + scatter ----
    if (tid < 64) {
        const int j = tid;
        const int c0 = (j < KK) ? cnt[j] : 0;
        const int t0 = (j < KK) ? ((c0 + 15) >> 4) : 0;
        int sc = c0, st = t0;
        #pragma unroll
        for (int off = 1; off < 32; off <<= 1) {
            const int vc = __shfl_up(sc, off);
            const int vt = __shfl_up(st, off);
            if (j >= off) { sc += vc; st += vt; }
        }
        if (j < KK) { sbase[j] = sc - c0; tstart[j] = st - t0; }
        if (j == KK) tstart[KK] = st;
    }
    __syncthreads();
    #pragma unroll
    for (int i = 0; i < 2; ++i) {
        const int c = tid + 256 * i;
        if (!(c & 1) && kq[i] >= 0) {
            const int rr = atomicAdd(&rnk[kq[i]], 1);
            sorted[sbase[kq[i]] + rr] = (unsigned short)(c >> 1);
        }
    }
    __syncthreads();

    // ---- Phase 3: MFMA tiles, ALL operands from LDS ----
    const int wave = tid >> 6;
    const int lrow = lane & 15;
    const int lgrp = lane >> 4;

    const int NT = tstart[KK];
    const int ts_l = tstart[(lane <= KK) ? lane : KK];

    for (int tix = wave; tix < NT; tix += 4) {
        const unsigned long long m = __ballot(ts_l <= tix);
        const int k = __builtin_amdgcn_readfirstlane(__popcll(m) - 1);

        const int sb = sbase[k];
        const int cn = cnt[k];
        const int r0 = (tix - tstart[k]) * 16;
        const int rl = r0 + lrow;

        const int R = sorted[sb + ((rl < cn) ? rl : 0)];

        // B: 2x ds_read_b64 of pre-rounded bf16 feats
        const unsigned* __restrict__ fr = fbf + R * FSTRIDE;
        const u32x2 wlo = *(const u32x2*)(fr + 2 * lgrp);
        const u32x2 whi = *(const u32x2*)(fr + 8 + 2 * lgrp);
        u32x4 bw; bw[0] = wlo[0]; bw[1] = wlo[1]; bw[2] = whi[0]; bw[3] = whi[1];
        const bf16x8 B = __builtin_bit_cast(bf16x8, bw);

        // A: 4x ds_read_b64 from compact W1^T (72B row stride)
        const unsigned short* __restrict__ wkp = sW1 + k * WK;
        const unsigned short* __restrict__ a0p = wkp + lrow * WROW + lgrp * 4;
        const unsigned short* __restrict__ a1p = a0p + 16 * WROW;
        const u32x2 alo0 = *(const u32x2*)a0p;
        const u32x2 ahi0 = *(const u32x2*)(a0p + 16);
        const u32x2 alo1 = *(const u32x2*)a1p;
        const u32x2 ahi1 = *(const u32x2*)(a1p + 16);
        u32x4 aw0; aw0[0] = alo0[0]; aw0[1] = alo0[1]; aw0[2] = ahi0[0]; aw0[3] = ahi0[1];
        u32x4 aw1; aw1[0] = alo1[0]; aw1[1] = alo1[1]; aw1[2] = ahi1[0]; aw1[3] = ahi1[1];
        const bf16x8 A0 = __builtin_bit_cast(bf16x8, aw0);
        const bf16x8 A1 = __builtin_bit_cast(bf16x8, aw1);

        // consts: broadcast b128 reads from sbw2
        const float* __restrict__ cp = sbw2 + k * 64 + 4 * lgrp;
        const f32x4 cb0 = *(const f32x4*)cp;
        const f32x4 cb1 = *(const f32x4*)(cp + 16);
        const f32x4 cw0 = *(const f32x4*)(cp + 32);
        const f32x4 cw1 = *(const f32x4*)(cp + 48);
        const float b2k = b2[k];

        f32x4 acc0 = {0.0f, 0.0f, 0.0f, 0.0f};
        f32x4 acc1 = {0.0f, 0.0f, 0.0f, 0.0f};
        acc0 = __builtin_amdgcn_mfma_f32_16x16x32_bf16(A0, B, acc0, 0, 0, 0);
        acc1 = __builtin_amdgcn_mfma_f32_16x16x32_bf16(A1, B, acc1, 0, 0, 0);

        float S = 0.0f;
        #pragma unroll
        for (int rr = 0; rr < 4; ++rr) {
            const float h0 = acc0[rr] + cb0[rr];
            const float q0 = (h0 >= 0.0f) ? h0 : 0.1f * h0;
            S = fmaf(q0, cw0[rr], S);
            const float h1 = acc1[rr] + cb1[rr];
            const float q1 = (h1 >= 0.0f) ? h1 : 0.1f * h1;
            S = fmaf(q1, cw1[rr], S);
        }
        S += __shfl_xor(S, 16);
        S += __shfl_xor(S, 32);

        if (lgrp == 0 && rl < cn) out[rowbase + R] = S + b2k;
    }
}

extern "C" void kernel_launch(void* const* d_in, const int* in_sizes, int n_in,
                              void* d_out, int out_size, void* d_ws, size_t ws_size,
                              hipStream_t stream) {
    const float* x  = (const float*)d_in[0];
    const float* a  = (const float*)d_in[1];
    const float* b  = (const float*)d_in[2];
    const float* W1 = (const float*)d_in[3];
    const float* b1 = (const float*)d_in[4];
    const float* W2 = (const float*)d_in[5];
    const float* b2 = (const float*)d_in[6];
    float* out = (float*)d_out;

    unsigned short* gW1bf = (unsigned short*)d_ws;          // 48384 B
    float* gbw2 = (float*)((char*)d_ws + W1BF_B);           // 5376 B

    hipLaunchKernelGGL(prep_kernel, dim3(KK), dim3(256), 0, stream,
                       W1, b1, W2, gW1bf, gbw2);

    hipLaunchKernelGGL(fused_kernel, dim3(NN / ROWS), dim3(256), 0, stream,
                       x, a, b, b2, gW1bf, gbw2, out);
}

// Round 13
// 20.597 us; speedup vs baseline: 1.4252x; 1.4252x over previous
//
#include <hip/hip_runtime.h>
#include <hip/hip_bf16.h>

#define NN 262144
#define DD 32
#define HH 31
#define KK 21
#define ROWS 256                 // rows per block (2 half-row chunks per thread)
#define FSTRIDE 18               // u32 words per feats row (72 B)
#define CSTRIDE 68               // floats per k in const table {b1[32],w2[32],b2,pad3}

typedef __attribute__((ext_vector_type(8))) short bf16x8;
typedef __attribute__((ext_vector_type(4))) float f32x4;
typedef __attribute__((ext_vector_type(2))) unsigned int u32x2;
typedef __attribute__((ext_vector_type(4))) unsigned int u32x4;

static __device__ __forceinline__ unsigned short f2bf(float f) {
    __hip_bfloat16 h = __float2bfloat16(f);      // round-to-nearest-even
    return __builtin_bit_cast(unsigned short, h);
}
static __device__ __forceinline__ float bf2f_dummy(unsigned short s) {
    unsigned u = ((unsigned)s) << 16;
    return __builtin_bit_cast(float, u);
}
static __device__ __forceinline__ unsigned pack2(float lo, float hi) {
    return (unsigned)f2bf(lo) | ((unsigned)f2bf(hi) << 16);
}

// ---------------- Prep: per-lane A-fragment tables + compact const table ----
__global__ __launch_bounds__(64) void prep_kernel(
    const float* __restrict__ W1, const float* __restrict__ b1,
    const float* __restrict__ W2, const float* __restrict__ b2,
    bf16x8* __restrict__ A0tab, bf16x8* __restrict__ A1tab,
    float* __restrict__ gcst)
{
    const int k = (int)blockIdx.x;
    const int lane = (int)threadIdx.x;
    const int lrow = lane & 15, lgrp = lane >> 4;
    const float* __restrict__ W1k = W1 + k * HH * HH;
    const int e0 = lrow, e1 = 16 + lrow;

    bf16x8 A0, A1;
    #pragma unroll
    for (int j = 0; j < 4; ++j) {
        const int d1 = 4 * lgrp + j;
        const int d2 = 16 + 4 * lgrp + j;
        A0[j]     = (short)f2bf(W1k[d1 * HH + e0]);
        A0[4 + j] = (d2 < HH) ? (short)f2bf(W1k[d2 * HH + e0]) : (short)0;
        A1[j]     = (e1 < HH) ? (short)f2bf(W1k[d1 * HH + e1]) : (short)0;
        A1[4 + j] = (e1 < HH && d2 < HH) ? (short)f2bf(W1k[d2 * HH + e1]) : (short)0;
    }
    A0tab[k * 64 + lane] = A0;
    A1tab[k * 64 + lane] = A1;

    for (int i = lane; i < CSTRIDE; i += 64) {
        float v = 0.0f;
        if (i < 32)       { if (i < HH) v = b1[k * HH + i]; }
        else if (i < 64)  { const int e = i - 32; if (e < HH) v = W2[k * HH + e]; }
        else if (i == 64) v = b2[k];
        gcst[k * CSTRIDE + i] = v;
    }
}

// ---------------- Fused: sort + software-pipelined MFMA ----------------
__global__ __launch_bounds__(256, 4) void fused_kernel(
    const float* __restrict__ x,
    const float* __restrict__ a,
    const float* __restrict__ b,
    const bf16x8* __restrict__ A0tab, const bf16x8* __restrict__ A1tab,
    const float* __restrict__ gcst,
    float* __restrict__ out)
{
    __shared__ unsigned fbf[ROWS * FSTRIDE];                  // 18432 B
    __shared__ __align__(16) float scst[KK * CSTRIDE];        // 5712 B
    __shared__ int cnt[KK];
    __shared__ int rnk[KK];
    __shared__ int sbase[KK];
    __shared__ int tstart[KK + 1];
    __shared__ unsigned short sorted[ROWS];

    const int tid = (int)threadIdx.x;
    const int lane = tid & 63;
    const int rowbase = (int)blockIdx.x * ROWS;

    if (tid < KK) { cnt[tid] = 0; rnk[tid] = 0; }

    // stage const table (5.7 KB, coalesced; overlaps x loads below)
    for (int i = tid; i < KK * CSTRIDE / 4; i += 256)
        ((f32x4*)scst)[i] = ((const f32x4*)gcst)[i];

    // ---- Phase 1: 2 half-row chunks/thread, 64 B/lane coalesced ----
    const float edges[KK + 1] = {
        0.0f, 0.1f, 0.2f, 0.3f, 0.4f, 0.5f, 0.6f, 0.7f, 0.8f, 0.9f, 1.0f,
        1.1f, 1.2f, 1.3f, 1.4f, 1.5f, 1.6f, 1.7f, 1.8f, 1.9f, 2.0f, 1000.0f
    };
    int kq[2] = {-1, -1};
    #pragma unroll
    for (int i = 0; i < 2; ++i) {
        const int c    = tid + 256 * i;
        const int row  = c >> 1;
        const int half = c & 1;
        const float4* __restrict__ p =
            reinterpret_cast<const float4*>(x) + (size_t)blockIdx.x * (ROWS * DD / 4) + c * 4;
        float4 cc[4];
        #pragma unroll
        for (int j = 0; j < 4; ++j) cc[j] = p[j];

        const float e16 = __shfl(cc[0].x, lane + 1);  // odd lane's elem 0 = x[16]
        const float t = cc[0].x;

        if (half == 0) {
            int kk = -1;
            #pragma unroll
            for (int j = 0; j < KK; ++j)
                if (t > edges[j] && t <= edges[j + 1]) kk = j;
            kq[i] = kk;
            if (kk >= 0) atomicAdd(&cnt[kk], 1);
            else out[rowbase + row] = 0.0f;
        }

        unsigned* __restrict__ frow = fbf + row * FSTRIDE + half * 8;
        if (half == 0) {
            float f[16];
            #pragma unroll
            for (int j = 0; j < 15; ++j)
                f[j] = fmaf(((const float*)cc)[j + 1], a[j], b[j]);
            f[15] = fmaf(e16, a[15], b[15]);
            #pragma unroll
            for (int s = 0; s < 8; ++s) frow[s] = pack2(f[2 * s], f[2 * s + 1]);
        } else {
            float f[16];
            #pragma unroll
            for (int j = 0; j < 15; ++j)
                f[j] = fmaf(((const float*)cc)[j + 1], a[16 + j], b[16 + j]);
            f[15] = 0.0f;
            #pragma unroll
            for (int s = 0; s < 8; ++s) frow[s] = pack2(f[2 * s], f[2 * s + 1]);
        }
    }
    __syncthreads();

    // ---- Phase 2: wave-parallel scan + scatter ----
    if (tid < 64) {
        const int j = tid;
        const int c0 = (j < KK) ? cnt[j] : 0;
        const int t0 = (j < KK) ? ((c0 + 15) >> 4) : 0;
        int sc = c0, st = t0;
        #pragma unroll
        for (int off = 1; off < 32; off <<= 1) {
            const int vc = __shfl_up(sc, off);
            const int vt = __shfl_up(st, off);
            if (j >= off) { sc += vc; st += vt; }
        }
        if (j < KK) { sbase[j] = sc - c0; tstart[j] = st - t0; }
        if (j == KK) tstart[KK] = st;
    }
    __syncthreads();
    #pragma unroll
    for (int i = 0; i < 2; ++i) {
        const int c = tid + 256 * i;
        if (!(c & 1) && kq[i] >= 0) {
            const int rr = atomicAdd(&rnk[kq[i]], 1);
            sorted[sbase[kq[i]] + rr] = (unsigned short)(c >> 1);
        }
    }
    __syncthreads();

    // ---- Phase 3: software-pipelined MFMA tiles ----
    const int wave = tid >> 6;
    const int lrow = lane & 15;
    const int lgrp = lane >> 4;

    const int NT = tstart[KK];
    const int ts_l = tstart[(lane <= KK) ? lane : KK];

    int tix = wave;
    int k0 = 0, cn0 = 0, rl0 = 0, R0 = 0;
    bf16x8 A0c = {}, A1c = {}, Bc = {};

    if (tix < NT) {
        const unsigned long long m = __ballot(ts_l <= tix);
        k0 = __builtin_amdgcn_readfirstlane(__popcll(m) - 1);
        cn0 = cnt[k0];
        rl0 = (tix - tstart[k0]) * 16 + lrow;
        R0 = sorted[sbase[k0] + ((rl0 < cn0) ? rl0 : 0)];
        const unsigned* __restrict__ fr = fbf + R0 * FSTRIDE;
        const u32x2 wlo = *(const u32x2*)(fr + 2 * lgrp);
        const u32x2 whi = *(const u32x2*)(fr + 8 + 2 * lgrp);
        u32x4 bw; bw[0] = wlo[0]; bw[1] = wlo[1]; bw[2] = whi[0]; bw[3] = whi[1];
        Bc = __builtin_bit_cast(bf16x8, bw);
        A0c = A0tab[k0 * 64 + lane];
        A1c = A1tab[k0 * 64 + lane];
    }

    while (tix < NT) {
        const int nxt = tix + 4;
        // ---- prefetch next tile's state (clamped when past the end) ----
        const int pt = (nxt < NT) ? nxt : tix;
        const unsigned long long m = __ballot(ts_l <= pt);
        const int k1 = __builtin_amdgcn_readfirstlane(__popcll(m) - 1);
        const int cn1 = cnt[k1];
        const int rl1 = (pt - tstart[k1]) * 16 + lrow;
        const int R1 = sorted[sbase[k1] + ((rl1 < cn1) ? rl1 : 0)];
        const unsigned* __restrict__ frn = fbf + R1 * FSTRIDE;
        const u32x2 nlo = *(const u32x2*)(frn + 2 * lgrp);
        const u32x2 nhi = *(const u32x2*)(frn + 8 + 2 * lgrp);
        u32x4 nw; nw[0] = nlo[0]; nw[1] = nlo[1]; nw[2] = nhi[0]; nw[3] = nhi[1];
        const bf16x8 Bn = __builtin_bit_cast(bf16x8, nw);
        const bf16x8 A0n = A0tab[k1 * 64 + lane];
        const bf16x8 A1n = A1tab[k1 * 64 + lane];

        // ---- compute current tile ----
        const float* __restrict__ cp = scst + k0 * CSTRIDE;
        const f32x4 cb0 = *(const f32x4*)(cp + 4 * lgrp);
        const f32x4 cb1 = *(const f32x4*)(cp + 16 + 4 * lgrp);
        const f32x4 cw0 = *(const f32x4*)(cp + 32 + 4 * lgrp);
        const f32x4 cw1 = *(const f32x4*)(cp + 48 + 4 * lgrp);
        const float b2k = cp[64];

        f32x4 acc0 = {0.0f, 0.0f, 0.0f, 0.0f};
        f32x4 acc1 = {0.0f, 0.0f, 0.0f, 0.0f};
        acc0 = __builtin_amdgcn_mfma_f32_16x16x32_bf16(A0c, Bc, acc0, 0, 0, 0);
        acc1 = __builtin_amdgcn_mfma_f32_16x16x32_bf16(A1c, Bc, acc1, 0, 0, 0);

        float S = 0.0f;
        #pragma unroll
        for (int rr = 0; rr < 4; ++rr) {
            const float h0 = acc0[rr] + cb0[rr];
            const float q0 = (h0 >= 0.0f) ? h0 : 0.1f * h0;
            S = fmaf(q0, cw0[rr], S);
            const float h1 = acc1[rr] + cb1[rr];
            const float q1 = (h1 >= 0.0f) ? h1 : 0.1f * h1;
            S = fmaf(q1, cw1[rr], S);
        }
        S += __shfl_xor(S, 16);
        S += __shfl_xor(S, 32);

        if (lgrp == 0 && rl0 < cn0) out[rowbase + R0] = S + b2k;

        // ---- rotate ----
        k0 = k1; cn0 = cn1; rl0 = rl1; R0 = R1;
        A0c = A0n; A1c = A1n; Bc = Bn;
        tix = nxt;
    }
}

extern "C" void kernel_launch(void* const* d_in, const int* in_sizes, int n_in,
                              void* d_out, int out_size, void* d_ws, size_t ws_size,
                              hipStream_t stream) {
    const float* x  = (const float*)d_in[0];
    const float* a  = (const float*)d_in[1];
    const float* b  = (const float*)d_in[2];
    const float* W1 = (const float*)d_in[3];
    const float* b1 = (const float*)d_in[4];
    const float* W2 = (const float*)d_in[5];
    const float* b2 = (const float*)d_in[6];
    float* out = (float*)d_out;

    char* ws = (char*)d_ws;
    bf16x8* A0tab = (bf16x8*)ws;                       // 21*64*16B
    bf16x8* A1tab = A0tab + KK * 64;                   // 21*64*16B
    float* gcst  = (float*)(A1tab + KK * 64);          // 21*68*4B

    hipLaunchKernelGGL(prep_kernel, dim3(KK), dim3(64), 0, stream,
                       W1, b1, W2, b2, A0tab, A1tab, gcst);

    hipLaunchKernelGGL(fused_kernel, dim3(NN / ROWS), dim3(256), 0, stream,
                       x, a, b, A0tab, A1tab, gcst, out);
}